// Round 1
// baseline (637.140 us; speedup 1.0000x reference)
//
#include <hip/hip_runtime.h>
#include <cmath>

namespace {
constexpr int T = 1024;
constexpr int BATCH = 128;
constexpr int U = 100;
constexpr int E = 100;
constexpr int P = 20;
constexpr int C = 2;
constexpr float DT = 0.001f;
constexpr float SCALE = 0.2f;
constexpr float MU = 1.0f;

__device__ __forceinline__ void euler5(float& xx, float& yy, float om, float drive) {
#pragma unroll
    for (int s = 0; s < 5; ++s) {
        float r2 = xx * xx + yy * yy;
        float d = MU - r2;
        float nx = xx + DT * (d * xx - om * yy + SCALE * drive);
        float ny = yy + DT * (d * yy + om * xx);
        xx = nx; yy = ny;
    }
}

__launch_bounds__(384, 2)
__global__ void donn_kernel(const int* __restrict__ x,
                            const float* __restrict__ emb,
                            const float* __restrict__ omega1,
                            const float* __restrict__ omega2,
                            const float* __restrict__ w1,
                            const float* __restrict__ b1,
                            const float* __restrict__ w2,
                            const float* __restrict__ b2,
                            const float* __restrict__ wp,
                            const float* __restrict__ bp,
                            const float* __restrict__ wh,
                            const float* __restrict__ bh,
                            float* __restrict__ out)
{
    const int b = blockIdx.x;
    const int tid = threadIdx.x;
    const int* xrow = x + b * T;

    __shared__ __align__(16) float zbuf[2][2][104];  // [parity][r/i][unit]
    __shared__ __align__(16) float pbuf[2][2][104];  // [parity][half][unit]
    __shared__ float h2s[104];
    __shared__ float h3s[32];

    const bool is_osc = (tid < 128);

    // ---- persistent per-role state ----
    float x1 = 0.f, y1 = 0.f, x2 = 0.f, y2 = 0.f;    // osc
    float om1 = 0.f, om2 = 0.f, b1j = 0.f;
    float u_cur = 0.f;
    int row_n = 0;
    int mj = 0, mh = 0;                               // mm
    float wreg[100];                                  // mm: half a w1 column in regs

    if (is_osc) {
        const int j = tid;
        const int jc = (j < U) ? j : (U - 1);
        om1 = omega1[jc];
        om2 = omega2[jc];
        b1j = b1[jc];
        if (j < U) u_cur = emb[xrow[0] * E + j];
        row_n = xrow[1];
    } else {
        mh = (tid >> 7) - 1;          // 0 or 1
        mj = tid & 127;
        const int jc = (mj < U) ? mj : (U - 1);
#pragma unroll
        for (int kk = 0; kk < 100; ++kk)
            wreg[kk] = w1[(100 * mh + kk) * U + jc];
    }

    // Pipelined main loop: phase t does
    //   osc: Euler2(t-2) [reads pbuf[t&1]], Euler1(t) [writes zbuf[t&1]]
    //   mm : matmul(t-1) [reads zbuf[(t-1)&1], writes pbuf[(t-1)&1]]
    // one barrier per phase; all producer->consumer pairs cross exactly one barrier.
    for (int t = 0; t < T; ++t) {
        if (is_osc) {
            const int j = tid;
            if (j < U) {
                // prefetch u(t+1) early so the load hides under the Euler chains
                float u_nxt = 0.f;
                if (t + 1 < T) u_nxt = emb[row_n * E + j];
                int row_nn = xrow[(t + 2 < T) ? (t + 2) : (T - 1)];

                if (t >= 2) {
                    float h1 = pbuf[t & 1][0][j] + pbuf[t & 1][1][j] + b1j;
                    h1 = fmaxf(h1, 0.f);
                    euler5(x2, y2, om2, h1);
                }
                euler5(x1, y1, om1, u_cur);
                zbuf[t & 1][0][j] = x1;
                zbuf[t & 1][1][j] = y1;
                u_cur = u_nxt;
                row_n = row_nn;
            }
        } else {
            if (t >= 1 && mj < U) {
                const float4* c4 = reinterpret_cast<const float4*>(&zbuf[(t - 1) & 1][mh][0]);
                float a0 = 0.f, a1 = 0.f, a2 = 0.f, a3 = 0.f;
#pragma unroll
                for (int q = 0; q < 25; ++q) {
                    float4 c = c4[q];   // broadcast read, all lanes same address
                    a0 = fmaf(c.x, wreg[4 * q + 0], a0);
                    a1 = fmaf(c.y, wreg[4 * q + 1], a1);
                    a2 = fmaf(c.z, wreg[4 * q + 2], a2);
                    a3 = fmaf(c.w, wreg[4 * q + 3], a3);
                }
                pbuf[(t - 1) & 1][mh][mj] = (a0 + a1) + (a2 + a3);
            }
        }
        __syncthreads();
    }

    // drain phase T: osc Euler2(T-2) [pbuf[0]], mm matmul(T-1) [zbuf[1] -> pbuf[1]]
    if (is_osc) {
        const int j = tid;
        if (j < U) {
            float h1 = pbuf[0][0][j] + pbuf[0][1][j] + b1j;
            h1 = fmaxf(h1, 0.f);
            euler5(x2, y2, om2, h1);
        }
    } else {
        if (mj < U) {
            const float4* c4 = reinterpret_cast<const float4*>(&zbuf[1][mh][0]);
            float a0 = 0.f, a1 = 0.f, a2 = 0.f, a3 = 0.f;
#pragma unroll
            for (int q = 0; q < 25; ++q) {
                float4 c = c4[q];
                a0 = fmaf(c.x, wreg[4 * q + 0], a0);
                a1 = fmaf(c.y, wreg[4 * q + 1], a1);
                a2 = fmaf(c.z, wreg[4 * q + 2], a2);
                a3 = fmaf(c.w, wreg[4 * q + 3], a3);
            }
            pbuf[1][mh][mj] = (a0 + a1) + (a2 + a3);
        }
    }
    __syncthreads();

    // drain phase T+1: osc Euler2(T-1); final z2 -> zbuf[0]
    if (is_osc && tid < U) {
        const int j = tid;
        float h1 = pbuf[1][0][j] + pbuf[1][1][j] + b1j;
        h1 = fmaxf(h1, 0.f);
        euler5(x2, y2, om2, h1);
        zbuf[0][0][j] = x2;
        zbuf[0][1][j] = y2;
    }
    __syncthreads();

    // one-shot w2 matmul with weights straight from global (L2-resident, 80 KB/block once)
    if (!is_osc && mj < U) {
        float acc = 0.f;
        const float* cv = &zbuf[0][mh][0];
#pragma unroll 8
        for (int kk = 0; kk < 100; ++kk)
            acc = fmaf(cv[kk], w2[(100 * mh + kk) * U + mj], acc);
        pbuf[0][mh][mj] = acc;
    }
    __syncthreads();

    if (tid < U) {
        float h2 = fmaxf(pbuf[0][0][tid] + pbuf[0][1][tid] + b2[tid], 0.f);
        h2s[tid] = h2;
    }
    __syncthreads();

    if (tid < P) {
        float acc = bp[tid];
#pragma unroll 4
        for (int j2 = 0; j2 < U; ++j2)
            acc = fmaf(h2s[j2], wp[j2 * P + tid], acc);
        h3s[tid] = tanhf(acc);
    }
    __syncthreads();

    if (tid < C) {
        float acc = bh[tid];
#pragma unroll
        for (int p = 0; p < P; ++p)
            acc = fmaf(h3s[p], wh[p * C + tid], acc);
        out[b * C + tid] = acc;
    }
}
} // namespace

extern "C" void kernel_launch(void* const* d_in, const int* in_sizes, int n_in,
                              void* d_out, int out_size, void* d_ws, size_t ws_size,
                              hipStream_t stream) {
    const int* xi        = (const int*)d_in[0];
    const float* emb     = (const float*)d_in[1];
    const float* omega1  = (const float*)d_in[2];
    const float* omega2  = (const float*)d_in[3];
    const float* w1      = (const float*)d_in[4];
    const float* b1      = (const float*)d_in[5];
    const float* w2      = (const float*)d_in[6];
    const float* b2      = (const float*)d_in[7];
    const float* wp      = (const float*)d_in[8];
    const float* bp      = (const float*)d_in[9];
    const float* wh      = (const float*)d_in[10];
    const float* bh      = (const float*)d_in[11];
    float* out           = (float*)d_out;

    hipLaunchKernelGGL(donn_kernel, dim3(BATCH), dim3(384), 0, stream,
                       xi, emb, omega1, omega2, w1, b1, w2, b2, wp, bp, wh, bh, out);
}

// Round 2
// 400.817 us; speedup vs baseline: 1.5896x; 1.5896x over previous
//
#include <hip/hip_runtime.h>
#include <cmath>

namespace {
constexpr int T = 1024, BATCH = 128, U = 100, E = 100, P = 20, C = 2;
constexpr int TC = 64, NC = 16;          // chunk size, number of chunks
constexpr float DT = 0.001f, SCALE = 0.2f, MU = 1.0f;

// ---- LDS byte layout (static char arena, 139264 B) ----
// ZB: [2][64 t][208 f16]   rows 416 B, XOR-swz by (t>>3)&7   @ 0      (53248)
// WL: [128 j][208 f16]     rows 416 B, XOR-swz by (j>>2)&7   @ 53248  (53248)
// HB: [2][64 t][128 f16]   rows 256 B, no swz                @ 106496 (32768)
constexpr uint32_t ZBUF = 26624u, WLB = 53248u, HBB = 106496u, HBUF = 16384u;

typedef _Float16 h2_t __attribute__((ext_vector_type(2)));
typedef _Float16 h4_t __attribute__((ext_vector_type(4)));
typedef _Float16 h8_t __attribute__((ext_vector_type(8)));
union H8 { h8_t v; h2_t p[4]; };

#if __has_builtin(__builtin_amdgcn_fdot2)
#define DOT2(a, b, c) __builtin_amdgcn_fdot2((a), (b), (c), false)
#else
#define DOT2(a, b, c) fmaf((float)(a)[1], (float)(b)[1], fmaf((float)(a)[0], (float)(b)[0], (c)))
#endif

__device__ __forceinline__ uint32_t zoff(int q, int t, int kb) {
    uint32_t lin = (uint32_t)(t * 416 + kb);
    lin ^= (((uint32_t)(t >> 3) & 7u) << 4);
    return (uint32_t)q * ZBUF + lin;
}
__device__ __forceinline__ uint32_t woff(int j, int kb) {
    uint32_t lin = (uint32_t)(j * 416 + kb);
    lin ^= (((uint32_t)(j >> 2) & 7u) << 4);
    return WLB + lin;
}
__device__ __forceinline__ uint32_t hoff(int q, int t, int j2b) {
    return HBB + (uint32_t)q * HBUF + (uint32_t)(t * 256 + j2b);
}

__device__ __forceinline__ void eul5(float& xx, float& yy, float dom, float ax) {
    // dom = DT*omega, ax = DT*SCALE*u, c0 = 1 + DT*MU
    constexpr float c0 = 1.0f + DT * MU;
#pragma unroll
    for (int s = 0; s < 5; ++s) {
        float r2 = fmaf(yy, yy, xx * xx);
        float sc = fmaf(-DT, r2, c0);
        float nx = fmaf(xx, sc, fmaf(-dom, yy, ax));
        float ny = fmaf(yy, sc, dom * xx);
        xx = nx; yy = ny;
    }
}

__launch_bounds__(512, 1)
__global__ void donn_kernel(const int* __restrict__ xg,
                            const float* __restrict__ emb,
                            const float* __restrict__ omega1,
                            const float* __restrict__ omega2,
                            const float* __restrict__ w1,
                            const float* __restrict__ b1,
                            const float* __restrict__ w2,
                            const float* __restrict__ b2,
                            const float* __restrict__ wp,
                            const float* __restrict__ bp,
                            const float* __restrict__ wh,
                            const float* __restrict__ bh,
                            float* __restrict__ out)
{
    const int b = blockIdx.x;
    const int tid = threadIdx.x;

    __shared__ __align__(16) char smem[139264];
    __shared__ int xs[2][TC];
    __shared__ float zf2[2][104];
    __shared__ float pb[2][104];
    __shared__ float h2s[104];
    __shared__ float h3s[32];

    // ---- role state ----
    float x1 = 0.f, y1 = 0.f, x2 = 0.f, y2 = 0.f;
    float dom1 = 0.f, dom2 = 0.f;
    int jc = 0;                      // clamped unit for osc roles
    int t0 = 0, j0 = 0;              // mm tile origin
    float b1r[4] = {0.f, 0.f, 0.f, 0.f};

    if (tid < 128) {                 // osc1: unit j = tid (active j<100)
        jc = (tid < U) ? tid : (U - 1);
        dom1 = DT * omega1[jc];
    } else if (tid < 256) {          // osc2: unit j = tid-128
        jc = (tid - 128 < U) ? (tid - 128) : (U - 1);
        dom2 = DT * omega2[jc];
    } else {                         // mm: 256 threads, grid 8tt x 32jj, tile 8t x 4j
        const int e = tid - 256;
        const int jj = e & 31, tt = e >> 5;
        t0 = tt * 8; j0 = jj * 4;
#pragma unroll
        for (int m = 0; m < 4; ++m) b1r[m] = (j0 + m < U) ? b1[j0 + m] : 0.f;
    }

    // ---- prologue: stage w1 (f16, transposed, swizzled) + x chunk 0 ----
    for (int idx = tid; idx < 128 * 200; idx += 512) {
        int kw = idx >> 7;           // 0..199
        int jw = idx & 127;          // 0..127
        float v = (jw < U) ? w1[kw * U + jw] : 0.f;
        *(_Float16*)(smem + woff(jw, 2 * kw)) = (_Float16)v;
    }
    if (tid < TC) xs[0][tid] = xg[b * T + tid];
    __syncthreads();

    // ---- 3-stage chunked pipeline, 18 phases ----
    // phase p: osc1 does chunk p -> ZB[p&1]; mm does chunk p-1: ZB -> HB[(p-1)&1];
    //          osc2 does chunk p-2 from HB[p&1]. One barrier per phase.
    for (int p = 0; p <= NC + 1; ++p) {
        if (tid < 128) {
            if (tid < TC && p + 1 < NC)
                xs[(p + 1) & 1][tid] = xg[b * T + (p + 1) * TC + tid];
            if (p < NC) {
                const int q = p & 1;
                const bool act = tid < U;
                float ue[8];
#pragma unroll
                for (int i = 0; i < 8; ++i) ue[i] = emb[xs[q][i] * E + jc];
#pragma unroll 8
                for (int tl = 0; tl < TC; ++tl) {
                    float uv = ue[tl & 7];
                    if (tl + 8 < TC) ue[tl & 7] = emb[xs[q][tl + 8] * E + jc];
                    eul5(x1, y1, dom1, (DT * SCALE) * uv);
                    if (act) {
                        *(_Float16*)(smem + zoff(q, tl, 2 * tid)) = (_Float16)x1;
                        *(_Float16*)(smem + zoff(q, tl, 2 * (tid + U))) = (_Float16)y1;
                    }
                }
            }
        } else if (tid < 256) {
            if (p >= 2) {
                const int q = (p - 2) & 1;
                const int j2 = tid - 128;   // <128, in-bounds of 128-wide HB row
#pragma unroll 4
                for (int tl = 0; tl < TC; ++tl) {
                    float h1 = (float)(*(const _Float16*)(smem + hoff(q, tl, 2 * j2)));
                    eul5(x2, y2, dom2, (DT * SCALE) * h1);
                }
            }
        } else {
            if (p >= 1 && p <= NC) {
                const int q = (p - 1) & 1;
                float acc[8][4];
#pragma unroll
                for (int i = 0; i < 8; ++i)
#pragma unroll
                    for (int m = 0; m < 4; ++m) acc[i][m] = 0.f;
                for (int k8 = 0; k8 < 25; ++k8) {
                    H8 zf[8]; H8 wf[4];
#pragma unroll
                    for (int i = 0; i < 8; ++i)
                        zf[i].v = *(const h8_t*)(smem + zoff(q, t0 + i, k8 * 16));
#pragma unroll
                    for (int m = 0; m < 4; ++m)
                        wf[m].v = *(const h8_t*)(smem + woff(j0 + m, k8 * 16));
#pragma unroll
                    for (int i = 0; i < 8; ++i)
#pragma unroll
                        for (int m = 0; m < 4; ++m) {
                            float a = acc[i][m];
                            a = DOT2(zf[i].p[0], wf[m].p[0], a);
                            a = DOT2(zf[i].p[1], wf[m].p[1], a);
                            a = DOT2(zf[i].p[2], wf[m].p[2], a);
                            a = DOT2(zf[i].p[3], wf[m].p[3], a);
                            acc[i][m] = a;
                        }
                }
#pragma unroll
                for (int i = 0; i < 8; ++i) {
                    h4_t r;
#pragma unroll
                    for (int m = 0; m < 4; ++m)
                        r[m] = (_Float16)fmaxf(acc[i][m] + b1r[m], 0.f);
                    *(h4_t*)(smem + hoff(q, t0 + i, 2 * j0)) = r;
                }
            }
        }
        __syncthreads();
    }

    // ---- final z2 -> LDS ----
    if (tid >= 128 && tid < 256) {
        const int j = tid - 128;
        if (j < U) { zf2[0][j] = x2; zf2[1][j] = y2; }
    }
    __syncthreads();

    // ---- one-shot epilogue: w2 GEMV (fp32, weights from global/L2) ----
    if (tid >= 256 && tid < 456) {
        const int e = tid - 256;
        const int h = e / 100, jq = e % 100;
        float acc2 = 0.f;
#pragma unroll 4
        for (int kk = 0; kk < 100; ++kk)
            acc2 = fmaf(zf2[h][kk], w2[(100 * h + kk) * U + jq], acc2);
        pb[h][jq] = acc2;
    }
    __syncthreads();

    if (tid < U) h2s[tid] = fmaxf(pb[0][tid] + pb[1][tid] + b2[tid], 0.f);
    __syncthreads();

    if (tid < P) {
        float acc = bp[tid];
#pragma unroll 4
        for (int j = 0; j < U; ++j) acc = fmaf(h2s[j], wp[j * P + tid], acc);
        h3s[tid] = tanhf(acc);
    }
    __syncthreads();

    if (tid < C) {
        float acc = bh[tid];
#pragma unroll
        for (int pp = 0; pp < P; ++pp) acc = fmaf(h3s[pp], wh[pp * C + tid], acc);
        out[b * C + tid] = acc;
    }
}
} // namespace

extern "C" void kernel_launch(void* const* d_in, const int* in_sizes, int n_in,
                              void* d_out, int out_size, void* d_ws, size_t ws_size,
                              hipStream_t stream) {
    const int* xi        = (const int*)d_in[0];
    const float* emb     = (const float*)d_in[1];
    const float* omega1  = (const float*)d_in[2];
    const float* omega2  = (const float*)d_in[3];
    const float* w1      = (const float*)d_in[4];
    const float* b1      = (const float*)d_in[5];
    const float* w2      = (const float*)d_in[6];
    const float* b2      = (const float*)d_in[7];
    const float* wp      = (const float*)d_in[8];
    const float* bp      = (const float*)d_in[9];
    const float* wh      = (const float*)d_in[10];
    const float* bh      = (const float*)d_in[11];
    float* out           = (float*)d_out;

    hipLaunchKernelGGL(donn_kernel, dim3(BATCH), dim3(512), 0, stream,
                       xi, emb, omega1, omega2, w1, b1, w2, b2, wp, bp, wh, bh, out);
}

// Round 3
// 340.303 us; speedup vs baseline: 1.8723x; 1.1778x over previous
//
#include <hip/hip_runtime.h>
#include <cmath>

namespace {
constexpr int T = 1024, BATCH = 128, U = 100, E = 100, P = 20, C = 2;
constexpr int TC = 64, NC = 16;          // chunk size, number of chunks
constexpr float DT = 0.001f, SCALE = 0.2f, MU = 1.0f;

// ---- LDS arena (byte offsets). No swizzles; conflict-free by access design.
// WL: [104 j][400 B]  f16 w1, k'-interleaved (k'=2k for k<U, 2(k-U)+1 else)
// ZB: [2][64 t][400 B] f16 z, k'-interleaved: (x_j,y_j) at bytes 4j
// HB: [2][64 t][216 B] f16 h1
// EB: [2][64 t][208 B] f16 u (embedded input)
constexpr uint32_t ROW400 = 400u;
constexpr uint32_t WLB = 0u;
constexpr uint32_t ZBB = 41600u, ZBUF = 25600u;
constexpr uint32_t HBB = 92800u, HBUF = 13824u, HROW = 216u;
constexpr uint32_t EBB = 120448u, EBUF = 13312u, EROW = 208u;

typedef _Float16 h2_t __attribute__((ext_vector_type(2)));
typedef _Float16 h8_t __attribute__((ext_vector_type(8)));
union H8 { h8_t v; h2_t p[4]; };

#if __has_builtin(__builtin_amdgcn_fdot2)
#define DOT2(a, b, c) __builtin_amdgcn_fdot2((a), (b), (c), false)
#else
#define DOT2(a, b, c) fmaf((float)(a)[1], (float)(b)[1], fmaf((float)(a)[0], (float)(b)[0], (c)))
#endif

__device__ __forceinline__ void eul5(float& xx, float& yy, float dom, float ax) {
    constexpr float c0 = 1.0f + DT * MU;   // dom = DT*omega, ax = DT*SCALE*drive
#pragma unroll
    for (int s = 0; s < 5; ++s) {
        float r2 = fmaf(yy, yy, xx * xx);
        float sc = fmaf(-DT, r2, c0);
        float nx = fmaf(xx, sc, fmaf(-dom, yy, ax));
        float ny = fmaf(yy, sc, dom * xx);
        xx = nx; yy = ny;
    }
}

__launch_bounds__(512, 1)
__global__ void donn_kernel(const int* __restrict__ xg,
                            const float* __restrict__ emb,
                            const float* __restrict__ omega1,
                            const float* __restrict__ omega2,
                            const float* __restrict__ w1,
                            const float* __restrict__ b1,
                            const float* __restrict__ w2,
                            const float* __restrict__ b2,
                            const float* __restrict__ wp,
                            const float* __restrict__ bp,
                            const float* __restrict__ wh,
                            const float* __restrict__ bh,
                            float* __restrict__ out)
{
    const int b = blockIdx.x;
    const int tid = threadIdx.x;

    __shared__ __align__(16) char smem[147072];
    __shared__ int xs[2][TC];
    __shared__ float zf2[2][104];
    __shared__ float pb[2][104];
    __shared__ float h2s[104];
    __shared__ float h3s[32];

    // ---- per-role persistent state ----
    float x1 = 0.f, y1 = 0.f, x2 = 0.f, y2 = 0.f;
    float dom1 = 0.f, dom2 = 0.f;
    int jc = 0, j2c = 0;
    int tt = 0, j0 = 0;
    float b1r[13];
    int urow[25], ucol[25];

    if (tid < 128) {                       // osc1: unit j = tid (j<100 active)
        jc = (tid < U) ? tid : (U - 1);
        dom1 = DT * omega1[jc];
    } else if (tid < 256) {                // osc2: unit j = tid-128
        const int j2 = tid - 128;
        j2c = (j2 < 104) ? j2 : 103;
        dom2 = DT * omega2[(j2 < U) ? j2 : (U - 1)];
    } else {                               // mm: 256 threads; tile 2t x 13j
        const int e = tid - 256;
        const int jj = e >> 5;             // 0..7
        tt = e & 31;                       // thread covers t = tt and tt+32
        j0 = jj * 13;
#pragma unroll
        for (int m = 0; m < 13; ++m) b1r[m] = (j0 + m < U) ? b1[j0 + m] : 0.f;
#pragma unroll
        for (int i = 0; i < 25; ++i) {     // EB staging element map (fixed)
            int idx = i * 256 + e;
            int row = idx / 100;
            urow[i] = row;
            ucol[i] = idx - 100 * row;
        }
    }

    // ---- prologue: WL (w1 f16, k'-interleaved), EB chunk 0, xs chunk 1 ----
    for (int idx = tid; idx < 104 * 200; idx += 512) {
        int k = idx / 104;                 // 0..199
        int j = idx - 104 * k;             // lanes: consecutive j -> coalesced w1 read
        float v = (j < U) ? w1[k * U + j] : 0.f;
        int kp = (k < U) ? (2 * k) : (2 * (k - U) + 1);
        *(_Float16*)(smem + WLB + (uint32_t)j * ROW400 + 2 * kp) = (_Float16)v;
    }
    for (int idx = tid; idx < TC * E; idx += 512) {
        int row = idx / 100;
        int col = idx - 100 * row;
        int tok = xg[b * T + row];
        float v = emb[tok * E + col];
        *(_Float16*)(smem + EBB + (uint32_t)row * EROW + 2 * col) = (_Float16)v;
    }
    if (tid < TC) xs[1][tid] = xg[b * T + TC + tid];
    __syncthreads();

    // ---- 3-stage chunked pipeline, one barrier per phase ----
    // phase p: osc1 chunk p (EB[p&1] -> ZB[p&1]); mm chunk p-1 (ZB -> HB) and
    // EB-prefetch chunk p+1; osc2 chunk p-2 (HB); osc2-threads xs-prefetch p+2.
    for (int p = 0; p <= NC + 1; ++p) {
        if (tid < 128) {
            if (p < NC) {
                const uint32_t q = (uint32_t)(p & 1);
                const char* eb = smem + EBB + q * EBUF;
                char* zb = smem + ZBB + q * ZBUF;
                const bool act = tid < U;
#pragma unroll 8
                for (int tl = 0; tl < TC; ++tl) {
                    float u = (float)(*(const _Float16*)(eb + (uint32_t)tl * EROW + 2 * jc));
                    eul5(x1, y1, dom1, (DT * SCALE) * u);
                    if (act) {
                        h2_t zz; zz[0] = (_Float16)x1; zz[1] = (_Float16)y1;
                        *(h2_t*)(zb + (uint32_t)tl * ROW400 + 4 * tid) = zz;
                    }
                }
            }
        } else if (tid < 256) {
            if (p >= 2) {
                const uint32_t q = (uint32_t)(p & 1);   // chunk p-2 parity == p&1
                const char* hb = smem + HBB + q * HBUF;
#pragma unroll 8
                for (int tl = 0; tl < TC; ++tl) {
                    float hv = (float)(*(const _Float16*)(hb + (uint32_t)tl * HROW + 2 * j2c));
                    eul5(x2, y2, dom2, (DT * SCALE) * hv);
                }
            }
            if (p + 2 < NC && tid < 128 + TC)
                xs[p & 1][tid - 128] = xg[b * T + (p + 2) * TC + (tid - 128)];
        } else {
            // A) issue emb prefetch loads for chunk p+1 (held in regs)
            float er[25];
            const bool edo = (p + 1 < NC);
            if (edo) {
                const int q2 = (p + 1) & 1;
#pragma unroll
                for (int i = 0; i < 25; ++i) {
                    int tok = xs[q2][urow[i]];
                    er[i] = emb[tok * E + ucol[i]];
                }
            }
            // B) matmul chunk p-1
            if (p >= 1 && p <= NC) {
                const uint32_t qm = (uint32_t)((p - 1) & 1);
                const char* zb = smem + ZBB + qm * ZBUF;
                float acc0[13], acc1[13];
#pragma unroll
                for (int m = 0; m < 13; ++m) { acc0[m] = 0.f; acc1[m] = 0.f; }
#pragma unroll 5
                for (int k8 = 0; k8 < 25; ++k8) {
                    H8 zf0, zf1;
                    zf0.v = *(const h8_t*)(zb + (uint32_t)tt * ROW400 + 16 * k8);
                    zf1.v = *(const h8_t*)(zb + (uint32_t)(tt + 32) * ROW400 + 16 * k8);
#pragma unroll
                    for (int m = 0; m < 13; ++m) {
                        H8 wf;
                        wf.v = *(const h8_t*)(smem + WLB + (uint32_t)(j0 + m) * ROW400 + 16 * k8);
                        float a0 = acc0[m], a1 = acc1[m];
                        a0 = DOT2(zf0.p[0], wf.p[0], a0);  a1 = DOT2(zf1.p[0], wf.p[0], a1);
                        a0 = DOT2(zf0.p[1], wf.p[1], a0);  a1 = DOT2(zf1.p[1], wf.p[1], a1);
                        a0 = DOT2(zf0.p[2], wf.p[2], a0);  a1 = DOT2(zf1.p[2], wf.p[2], a1);
                        a0 = DOT2(zf0.p[3], wf.p[3], a0);  a1 = DOT2(zf1.p[3], wf.p[3], a1);
                        acc0[m] = a0; acc1[m] = a1;
                    }
                }
                char* hb = smem + HBB + qm * HBUF;
#pragma unroll
                for (int m = 0; m < 13; ++m) {
                    *(_Float16*)(hb + (uint32_t)tt * HROW + 2 * (j0 + m)) =
                        (_Float16)fmaxf(acc0[m] + b1r[m], 0.f);
                    *(_Float16*)(hb + (uint32_t)(tt + 32) * HROW + 2 * (j0 + m)) =
                        (_Float16)fmaxf(acc1[m] + b1r[m], 0.f);
                }
            }
            // C) write back emb prefetch (vmcnt waits land here, after matmul)
            if (edo) {
                const int q2 = (p + 1) & 1;
                char* eb = smem + EBB + (uint32_t)q2 * EBUF;
#pragma unroll
                for (int i = 0; i < 25; ++i)
                    *(_Float16*)(eb + (uint32_t)urow[i] * EROW + 2 * ucol[i]) = (_Float16)er[i];
            }
        }
        __syncthreads();
    }

    // ---- epilogue ----
    if (tid >= 128 && tid < 256) {
        const int j = tid - 128;
        if (j < U) { zf2[0][j] = x2; zf2[1][j] = y2; }
    }
    __syncthreads();

    if (tid >= 256 && tid < 456) {
        const int e = tid - 256;
        const int h = e / 100, jq = e - 100 * (e / 100);
        float acc2 = 0.f;
#pragma unroll 4
        for (int kk = 0; kk < 100; ++kk)
            acc2 = fmaf(zf2[h][kk], w2[(100 * h + kk) * U + jq], acc2);
        pb[h][jq] = acc2;
    }
    __syncthreads();

    if (tid < U) h2s[tid] = fmaxf(pb[0][tid] + pb[1][tid] + b2[tid], 0.f);
    __syncthreads();

    if (tid < P) {
        float acc = bp[tid];
#pragma unroll 4
        for (int j = 0; j < U; ++j) acc = fmaf(h2s[j], wp[j * P + tid], acc);
        h3s[tid] = tanhf(acc);
    }
    __syncthreads();

    if (tid < C) {
        float acc = bh[tid];
#pragma unroll
        for (int pp = 0; pp < P; ++pp) acc = fmaf(h3s[pp], wh[pp * C + tid], acc);
        out[b * C + tid] = acc;
    }
}
} // namespace

extern "C" void kernel_launch(void* const* d_in, const int* in_sizes, int n_in,
                              void* d_out, int out_size, void* d_ws, size_t ws_size,
                              hipStream_t stream) {
    const int* xi        = (const int*)d_in[0];
    const float* emb     = (const float*)d_in[1];
    const float* omega1  = (const float*)d_in[2];
    const float* omega2  = (const float*)d_in[3];
    const float* w1      = (const float*)d_in[4];
    const float* b1      = (const float*)d_in[5];
    const float* w2      = (const float*)d_in[6];
    const float* b2      = (const float*)d_in[7];
    const float* wp      = (const float*)d_in[8];
    const float* bp      = (const float*)d_in[9];
    const float* wh      = (const float*)d_in[10];
    const float* bh      = (const float*)d_in[11];
    float* out           = (float*)d_out;

    hipLaunchKernelGGL(donn_kernel, dim3(BATCH), dim3(512), 0, stream,
                       xi, emb, omega1, omega2, w1, b1, w2, b2, wp, bp, wh, bh, out);
}

// Round 4
// 149.641 us; speedup vs baseline: 4.2578x; 2.2741x over previous
//
#include <hip/hip_runtime.h>
#include <cmath>

namespace {
constexpr int T = 1024, BATCH = 128, U = 100, E = 100, P = 20, C = 2;
constexpr int TC = 64, NC = 16;          // chunk size, number of chunks
constexpr float DT = 0.001f, SCALE = 0.2f, MU = 1.0f;

// ---- LDS arena (byte offsets) ----
// WL: [100 j][464 B]  f16 w1, k'-interleaved (k'=2k for k<U else 2(k-U)+1), pad [400,464)=0
// ZB: [2][64 t][464 B] f16 z, k'-interleaved (x_j at 4j, y_j at 4j+2), pad [400,464)=0
// HB: [2][64 t][200 B] f16 h1
// EB: [2][64 t][200 B] f16 u
constexpr uint32_t WROW = 464u, ZROW = 464u, HROW = 200u, EROW = 200u;
constexpr uint32_t WLB = 0u;
constexpr uint32_t ZBB = 46400u, ZBUF = 64u * ZROW;     // 29696
constexpr uint32_t HBB = ZBB + 2u * ZBUF;               // 105792
constexpr uint32_t HBUF = 64u * HROW;                   // 12800
constexpr uint32_t EBB = HBB + 2u * HBUF;               // 131392
constexpr uint32_t EBUF = 64u * EROW;                   // 12800
constexpr uint32_t ARENA = EBB + 2u * EBUF;             // 156992

typedef _Float16 f16x8 __attribute__((ext_vector_type(8)));
typedef float f32x4 __attribute__((ext_vector_type(4)));
typedef _Float16 h2_t __attribute__((ext_vector_type(2)));

__device__ __forceinline__ void eul5(float& xx, float& yy, float dom, float ax) {
    constexpr float c0 = 1.0f + DT * MU;   // dom = DT*omega, ax = DT*SCALE*drive
#pragma unroll
    for (int s = 0; s < 5; ++s) {
        float r2 = fmaf(yy, yy, xx * xx);
        float sc = fmaf(-DT, r2, c0);
        float nx = fmaf(xx, sc, fmaf(-dom, yy, ax));
        float ny = fmaf(yy, sc, dom * xx);
        xx = nx; yy = ny;
    }
}

__launch_bounds__(512, 1)
__global__ void donn_kernel(const int* __restrict__ xg,
                            const float* __restrict__ emb,
                            const float* __restrict__ omega1,
                            const float* __restrict__ omega2,
                            const float* __restrict__ w1,
                            const float* __restrict__ b1,
                            const float* __restrict__ w2,
                            const float* __restrict__ b2,
                            const float* __restrict__ wp,
                            const float* __restrict__ bp,
                            const float* __restrict__ wh,
                            const float* __restrict__ bh,
                            float* __restrict__ out)
{
    const int b = blockIdx.x;
    const int tid = threadIdx.x;

    __shared__ __align__(16) char smem[ARENA];
    __shared__ int xs[2][TC];
    __shared__ float zf2[2][104];
    __shared__ float pb[2][104];
    __shared__ float h2s[104];
    __shared__ float h3s[32];

    // ---- per-role persistent state ----
    float x1 = 0.f, y1 = 0.f, x2 = 0.f, y2 = 0.f;
    float dom1 = 0.f, dom2 = 0.f;
    int jc = 0, j2c = 0;
    int mw = 0, lane = 0;
    float b1r[7];
    uint32_t brow[7];                      // B-frag row base addrs (clamped)
    int urow[25], ucol[25];

    if (tid < 128) {                       // osc1: unit j = tid (j<100 active)
        jc = (tid < U) ? tid : (U - 1);
        dom1 = DT * omega1[jc];
    } else if (tid < 256) {                // osc2: unit j = tid-128
        const int j2 = tid - 128;
        j2c = (j2 < U) ? j2 : (U - 1);
        dom2 = DT * omega2[j2c];
    } else {                               // mm: 4 waves; wave = m-block, MFMA GEMM
        mw = (tid >> 6) - 4;               // 0..3
        lane = tid & 63;
#pragma unroll
        for (int n = 0; n < 7; ++n) {
            int j = n * 16 + (lane & 15);
            int jj = (j < U) ? j : (U - 1);
            b1r[n] = b1[jj];
            brow[n] = WLB + (uint32_t)jj * WROW + 16u * (uint32_t)(lane >> 4);
        }
        const int e = tid - 256;
#pragma unroll
        for (int i = 0; i < 25; ++i) {     // EB staging element map
            int idx = i * 256 + e;
            int row = idx / 100;
            urow[i] = row;
            ucol[i] = idx - 100 * row;
        }
    }

    // ---- prologue ----
    // w1 -> WL (f16, k'-interleaved); lanes j-consecutive -> coalesced
    for (int idx = tid; idx < 200 * 100; idx += 512) {
        int k = idx / 100, j = idx - 100 * k;
        float v = w1[k * U + j];
        int kp = (k < U) ? (2 * k) : (2 * (k - U) + 1);
        *(_Float16*)(smem + WLB + (uint32_t)j * WROW + 2 * kp) = (_Float16)v;
    }
    // zero pads: WL rows 0..99 and ZB rows (2x64), bytes [400,464)
    for (int idx = tid; idx < 228 * 16; idx += 512) {
        int row = idx >> 4, wd = idx & 15;
        uint32_t base;
        if (row < 100) base = WLB + (uint32_t)row * WROW;
        else {
            int zr = row - 100;
            base = ZBB + (uint32_t)(zr >> 6) * ZBUF + (uint32_t)(zr & 63) * ZROW;
        }
        *(float*)(smem + base + 400u + 4u * (uint32_t)wd) = 0.f;
    }
    // EB chunk 0
    for (int idx = tid; idx < TC * E; idx += 512) {
        int row = idx / 100, col = idx - 100 * row;
        int tok = xg[b * T + row];
        *(_Float16*)(smem + EBB + (uint32_t)row * EROW + 2 * col) = (_Float16)emb[tok * E + col];
    }
    if (tid < TC) xs[1][tid] = xg[b * T + TC + tid];
    __syncthreads();

    // ---- 3-stage chunked pipeline, one barrier per phase ----
    for (int p = 0; p <= NC + 1; ++p) {
        if (tid < 128) {
            if (p < NC) {
                const uint32_t q = (uint32_t)(p & 1);
                const char* eb = smem + EBB + q * EBUF;
                char* zb = smem + ZBB + q * ZBUF;
                const bool act = tid < U;
#pragma unroll 8
                for (int tl = 0; tl < TC; ++tl) {
                    float u = (float)(*(const _Float16*)(eb + (uint32_t)tl * EROW + 2 * jc));
                    eul5(x1, y1, dom1, (DT * SCALE) * u);
                    if (act) {
                        h2_t zz; zz[0] = (_Float16)x1; zz[1] = (_Float16)y1;
                        *(h2_t*)(zb + (uint32_t)tl * ZROW + 4u * (uint32_t)tid) = zz;
                    }
                }
            }
        } else if (tid < 256) {
            if (p >= 2) {
                const uint32_t q = (uint32_t)(p & 1);   // chunk p-2 parity
                const char* hb = smem + HBB + q * HBUF;
#pragma unroll 8
                for (int tl = 0; tl < TC; ++tl) {
                    float hv = (float)(*(const _Float16*)(hb + (uint32_t)tl * HROW + 2 * j2c));
                    eul5(x2, y2, dom2, (DT * SCALE) * hv);
                }
            }
            if (p + 2 < NC && tid - 128 < TC)
                xs[p & 1][tid - 128] = xg[b * T + (p + 2) * TC + (tid - 128)];
        } else {
            // A) issue emb prefetch loads for chunk p+1 (held in regs)
            float er[25];
            const bool edo = (p + 1 < NC);
            if (edo) {
                const int q2 = (p + 1) & 1;
#pragma unroll
                for (int i = 0; i < 25; ++i) {
                    int tok = xs[q2][urow[i]];
                    er[i] = emb[tok * E + ucol[i]];
                }
            }
            // B) MFMA GEMM for chunk p-1: C[64t x 100j] = z[64x224] * w1'[224x100]
            if (p >= 1 && p <= NC) {
                const uint32_t qm = (uint32_t)((p - 1) & 1);
                const char* zb = smem + ZBB + qm * ZBUF;
                const uint32_t arow = (uint32_t)(mw * 16 + (lane & 15)) * ZROW
                                      + 16u * (uint32_t)(lane >> 4);
                f32x4 acc[7];
#pragma unroll
                for (int n = 0; n < 7; ++n) acc[n] = (f32x4)0.f;
#pragma unroll
                for (int ks = 0; ks < 7; ++ks) {
                    f16x8 af = *(const f16x8*)(zb + arow + 64u * ks);
#pragma unroll
                    for (int n = 0; n < 7; ++n) {
                        f16x8 bf = *(const f16x8*)(smem + brow[n] + 64u * ks);
                        acc[n] = __builtin_amdgcn_mfma_f32_16x16x32_f16(af, bf, acc[n], 0, 0, 0);
                    }
                }
                // C-write: row=(lane>>4)*4+r, col=lane&15 (m89-verified layout)
                char* hb = smem + HBB + qm * HBUF;
#pragma unroll
                for (int n = 0; n < 7; ++n) {
                    const int j = n * 16 + (lane & 15);
                    if (j < U) {
#pragma unroll
                        for (int r = 0; r < 4; ++r) {
                            int t = mw * 16 + (lane >> 4) * 4 + r;
                            float h = fmaxf(acc[n][r] + b1r[n], 0.f);
                            *(_Float16*)(hb + (uint32_t)t * HROW + 2 * j) = (_Float16)h;
                        }
                    }
                }
            }
            // C) write back emb prefetch
            if (edo) {
                const int q2 = (p + 1) & 1;
                char* eb = smem + EBB + (uint32_t)q2 * EBUF;
#pragma unroll
                for (int i = 0; i < 25; ++i)
                    *(_Float16*)(eb + (uint32_t)urow[i] * EROW + 2 * ucol[i]) = (_Float16)er[i];
            }
        }
        __syncthreads();
    }

    // ---- epilogue ----
    if (tid >= 128 && tid < 256) {
        const int j = tid - 128;
        if (j < U) { zf2[0][j] = x2; zf2[1][j] = y2; }
    }
    __syncthreads();

    if (tid >= 256 && tid < 456) {
        const int e = tid - 256;
        const int h = e / 100, jq = e - 100 * (e / 100);
        float acc2 = 0.f;
#pragma unroll 4
        for (int kk = 0; kk < 100; ++kk)
            acc2 = fmaf(zf2[h][kk], w2[(100 * h + kk) * U + jq], acc2);
        pb[h][jq] = acc2;
    }
    __syncthreads();

    if (tid < U) h2s[tid] = fmaxf(pb[0][tid] + pb[1][tid] + b2[tid], 0.f);
    __syncthreads();

    if (tid < P) {
        float acc = bp[tid];
#pragma unroll 4
        for (int j = 0; j < U; ++j) acc = fmaf(h2s[j], wp[j * P + tid], acc);
        h3s[tid] = tanhf(acc);
    }
    __syncthreads();

    if (tid < C) {
        float acc = bh[tid];
#pragma unroll
        for (int pp = 0; pp < P; ++pp) acc = fmaf(h3s[pp], wh[pp * C + tid], acc);
        out[b * C + tid] = acc;
    }
}
} // namespace

extern "C" void kernel_launch(void* const* d_in, const int* in_sizes, int n_in,
                              void* d_out, int out_size, void* d_ws, size_t ws_size,
                              hipStream_t stream) {
    const int* xi        = (const int*)d_in[0];
    const float* emb     = (const float*)d_in[1];
    const float* omega1  = (const float*)d_in[2];
    const float* omega2  = (const float*)d_in[3];
    const float* w1      = (const float*)d_in[4];
    const float* b1      = (const float*)d_in[5];
    const float* w2      = (const float*)d_in[6];
    const float* b2      = (const float*)d_in[7];
    const float* wp      = (const float*)d_in[8];
    const float* bp      = (const float*)d_in[9];
    const float* wh      = (const float*)d_in[10];
    const float* bh      = (const float*)d_in[11];
    float* out           = (float*)d_out;

    hipLaunchKernelGGL(donn_kernel, dim3(BATCH), dim3(512), 0, stream,
                       xi, emb, omega1, omega2, w1, b1, w2, b2, wp, bp, wh, bh, out);
}